// Round 16
// baseline (10399.171 us; speedup 1.0000x reference)
//
#include <hip/hip_runtime.h>

#define TT 4096

typedef __attribute__((ext_vector_type(2))) unsigned int u2v;
typedef __attribute__((ext_vector_type(4))) unsigned int u4v;
typedef __attribute__((ext_vector_type(2))) __fp16 f16x2;
typedef __attribute__((ext_vector_type(2))) _Float16 F16x2;
union HU { unsigned int u; f16x2 hf; F16x2 hF; };

// ws layout (float offsets):
//   M    @ 0      : 2048*64 = 131072   (W_in @ C)
//   wtil @ 131072 : 64                 (C^T @ dense_W[:64])
//   yp   @ 131200 : 4096*32 = 131072   (per-WG dense partials, 32 WGs)
//   hpub @ 393344 : 2 slots * 1024 packets * (u32 data, u32 tag) = 4096 u32
// hpub needs NO init: harness poisons ws to 0xAA -> tag never matches t+1.
//
// LAWS (confirmed): publish = ONE coalesced burst from ONE wave after a
// gather barrier (r1/r2/r6). Publisher wave != poller wave (r9, -500us).
// Cross-lane reduce + LDS h-streaming are real walls (r14 -360us, r15
// -195us). FALSIFIED: reader contention (r2/r4 replication, r13
// throttling), poll sampling quantization (r7), nt/MALL (r8), barrier
// vmcnt drains (r7). CURSED: 256-thread launches (r11/r12).
// r16 THEORY (last untested axis): detect latency scales with PARTICIPANT
// COUNT (straggler-max over producers + fabric load from pollers). Halve
// to 32 WGs x 64 rows: all 16 waves compute 4 rows (quarter-wave, r15's
// proven pattern -- protocol waves were compute-idle anyway), wave1
// publishes ONE 32-packet burst, wave0 polls the unchanged 1024-packet
// board. Wire format + packet<->row mapping (p <-> rows 2p,2p+1)
// byte-identical. Cost: unique h-LDS/WG doubles (+~250cy, known ladder).
// Outcome separates cleanly: participant-driven -> dur ~7.5-8.2ms and
// FETCH halves; latency-floor -> dur flat-ish, FETCH still halves.

__global__ void esn_prep(const float* __restrict__ C,
                         const float* __restrict__ Win,
                         const float* __restrict__ dW,
                         float* __restrict__ M,
                         float* __restrict__ wtil) {
  __shared__ float s[64];
  const int b = blockIdx.x, i = threadIdx.x;
  if (b < 2048) {
    s[i] = Win[b * 64 + i];
    __syncthreads();
    float acc = 0.f;
#pragma unroll 16
    for (int d = 0; d < 64; ++d) acc += s[d] * C[d * 64 + i];
    M[b * 64 + i] = acc;
  } else {
    s[i] = dW[i];
    __syncthreads();
    float acc = 0.f;
    for (int d = 0; d < 64; ++d) acc += s[d] * C[d * 64 + i];
    wtil[i] = acc;
  }
}

// Call-free tanh: tanh(x) = 1 - 2/(exp(2x)+1)
__device__ __forceinline__ float fast_tanh(float x) {
  const float e = __builtin_amdgcn_exp2f(x * 2.8853900817779268f);  // exp(2x)
  return 1.0f - 2.0f * __builtin_amdgcn_rcpf(e + 1.0f);
}

// fp16-pair dot with fp32 accumulate: v_dot2_f32_f16 where available.
__device__ __forceinline__ float fdot2f(const HU a, const HU b, float c) {
#if __has_builtin(__builtin_amdgcn_fdot2)
  return __builtin_amdgcn_fdot2(a.hF, b.hF, c, false);
#else
  return c + (float)a.hf.x * (float)b.hf.x + (float)a.hf.y * (float)b.hf.y;
#endif
}

// 32 WGs x 1024 threads. ALL 16 waves compute 4 rows each (quarter-wave:
// one row per 16-lane quarter). After bar1: wave1 publishes (lanes 0-31),
// wave0 polls, wave2 lane0 writes yp.
__global__ __launch_bounds__(1024) void esn_recur(
    const float* __restrict__ X, const float* __restrict__ M,
    const float* __restrict__ W, const float* __restrict__ dW,
    unsigned int* __restrict__ hpub, float* __restrict__ yp) {
  __shared__ unsigned int shh[1024];  // 2048 fp16 h as packed pairs
  __shared__ unsigned int pub[32];    // packed h pairs (2 per wave)
  __shared__ float psm[16];           // per-wave dense partials
  const int tid = threadIdx.x;
  const int lane = tid & 63;
  const int wave = tid >> 6;          // 0..15, all compute
  const int b = blockIdx.x;           // 0..31
  const int q = lane >> 4;            // quarter 0..3 -> row offset
  const int ql = lane & 15;
  const int row0 = b * 64 + wave * 4;
  const int row = row0 + q;
  float m[4], dwv[4];
#pragma unroll
  for (int j = 0; j < 4; ++j) m[j] = M[row * 64 + ql + 16 * j];
#pragma unroll
  for (int r = 0; r < 4; ++r) dwv[r] = dW[64 + row0 + r];
  // this lane's W fragment: row's pair-chunks {4ql+64m}, m=0..15
  // -> fp32 elements [8ql+128m .. +7]: two float4 per m. 64 VGPRs.
  u4v w[16];
#pragma unroll
  for (int mm = 0; mm < 16; ++mm) {
    const float* p = W + (size_t)row * 2048 + 128 * mm + 8 * ql;
    const float4 a = *(const float4*)p;
    const float4 c = *(const float4*)(p + 4);
    HU t0, t1, t2, t3;
    t0.hf = __builtin_amdgcn_cvt_pkrtz(a.x, a.y);
    t1.hf = __builtin_amdgcn_cvt_pkrtz(a.z, a.w);
    t2.hf = __builtin_amdgcn_cvt_pkrtz(c.x, c.y);
    t3.hf = __builtin_amdgcn_cvt_pkrtz(c.z, c.w);
    w[mm][0] = t0.u; w[mm][1] = t1.u; w[mm][2] = t2.u; w[mm][3] = t3.u;
  }
  shh[tid] = 0u;  // h_{-1} = 0
  __syncthreads();

  for (int t = 0; t < TT; ++t) {
    // X loads issued at loop top, consumed AFTER the dot phase (~hidden)
    float xr[4];
#pragma unroll
    for (int j = 0; j < 4; ++j) xr[j] = X[t * 64 + ql + 16 * j];
    float acc = 0.f;
#pragma unroll
    for (int mm = 0; mm < 16; ++mm) {
      // lanes ql+16k read the same addr -> 4-way broadcast;
      // across ql: 16B stride -> conflict-free ds_read_b128.
      const u4v hv = *(const u4v*)(shh + 4 * ql + 64 * mm);
#pragma unroll
      for (int k = 0; k < 4; ++k) {
        HU ha, wv;
        ha.u = hv[k]; wv.u = w[mm][k];
        acc = fdot2f(wv, ha, acc);
      }
    }
    acc += m[0] * xr[0] + m[1] * xr[1] + m[2] * xr[2] + m[3] * xr[3];
    // in-quarter reduce + gather the 4 quarter-sums to lane 0
#pragma unroll
    for (int off = 8; off; off >>= 1) acc += __shfl_xor(acc, off, 64);
    const float s1 = __shfl(acc, 16, 64);
    const float s2 = __shfl(acc, 32, 64);
    const float s3 = __shfl(acc, 48, 64);
    if (lane == 0) {
      const float h0 = fast_tanh(acc);
      const float h1 = fast_tanh(s1);
      const float h2 = fast_tanh(s2);
      const float h3 = fast_tanh(s3);
      HU pa, pb;
      pa.hf = __builtin_amdgcn_cvt_pkrtz(h0, h1);
      pb.hf = __builtin_amdgcn_cvt_pkrtz(h2, h3);
      pub[2 * wave] = pa.u;
      pub[2 * wave + 1] = pb.u;
      psm[wave] = dwv[0] * h0 + dwv[1] * h1 + dwv[2] * h2 + dwv[3] * h3;
    }
    __syncthreads();  // bar1: pub + psm ready; all shh reads of step t done
    const unsigned tg = (unsigned)t + 1u;
    unsigned int* slot = hpub + ((t & 1) << 11);
    if (wave == 1) {
      // publish: ONE coalesced 32-packet burst from wave1 (NOT the poller)
      if (t + 1 < TT && lane < 32) {
        u2v pv; pv.x = pub[lane]; pv.y = tg;
        asm volatile("global_store_dwordx2 %0, %1, off sc0 sc1"
                     :: "v"(slot + 2 * (32 * b + lane)), "v"(pv) : "memory");
      }
    } else if (wave == 0) {
      if (t + 1 < TT) {
        // poll: lane L owns packets {64p+L}; 16 loads in flight per round;
        // vmcnt(0) drains loads only -- never a store ack (r9 law).
        // (wave0's compute X loads are long complete by now.)
        const unsigned int* b0 = slot + 2 * lane;
        const unsigned int* b1 = b0 + 1024;
        u2v q0, q1, q2, q3, q4, q5, q6, q7, q8, q9, qa, qb, qc, qd, qe, qf;
        for (;;) {
          asm volatile(
              "global_load_dwordx2 %0, %16, off sc0 sc1\n\t"
              "global_load_dwordx2 %1, %16, off offset:512 sc0 sc1\n\t"
              "global_load_dwordx2 %2, %16, off offset:1024 sc0 sc1\n\t"
              "global_load_dwordx2 %3, %16, off offset:1536 sc0 sc1\n\t"
              "global_load_dwordx2 %4, %16, off offset:2048 sc0 sc1\n\t"
              "global_load_dwordx2 %5, %16, off offset:2560 sc0 sc1\n\t"
              "global_load_dwordx2 %6, %16, off offset:3072 sc0 sc1\n\t"
              "global_load_dwordx2 %7, %16, off offset:3584 sc0 sc1\n\t"
              "global_load_dwordx2 %8, %17, off sc0 sc1\n\t"
              "global_load_dwordx2 %9, %17, off offset:512 sc0 sc1\n\t"
              "global_load_dwordx2 %10, %17, off offset:1024 sc0 sc1\n\t"
              "global_load_dwordx2 %11, %17, off offset:1536 sc0 sc1\n\t"
              "global_load_dwordx2 %12, %17, off offset:2048 sc0 sc1\n\t"
              "global_load_dwordx2 %13, %17, off offset:2560 sc0 sc1\n\t"
              "global_load_dwordx2 %14, %17, off offset:3072 sc0 sc1\n\t"
              "global_load_dwordx2 %15, %17, off offset:3584 sc0 sc1\n\t"
              "s_waitcnt vmcnt(0)"
              : "=&v"(q0), "=&v"(q1), "=&v"(q2), "=&v"(q3),
                "=&v"(q4), "=&v"(q5), "=&v"(q6), "=&v"(q7),
                "=&v"(q8), "=&v"(q9), "=&v"(qa), "=&v"(qb),
                "=&v"(qc), "=&v"(qd), "=&v"(qe), "=&v"(qf)
              : "v"(b0), "v"(b1)
              : "memory");
          bool ok = (q0.y == tg) && (q1.y == tg) && (q2.y == tg) &&
                    (q3.y == tg) && (q4.y == tg) && (q5.y == tg) &&
                    (q6.y == tg) && (q7.y == tg) && (q8.y == tg) &&
                    (q9.y == tg) && (qa.y == tg) && (qb.y == tg) &&
                    (qc.y == tg) && (qd.y == tg) && (qe.y == tg) &&
                    (qf.y == tg);
          if (__all(ok)) break;
        }
        // repack: shh[64p + lane] -- stride-1 across lanes, conflict-free
        shh[lane] = q0.x;          shh[64 + lane] = q1.x;
        shh[128 + lane] = q2.x;    shh[192 + lane] = q3.x;
        shh[256 + lane] = q4.x;    shh[320 + lane] = q5.x;
        shh[384 + lane] = q6.x;    shh[448 + lane] = q7.x;
        shh[512 + lane] = q8.x;    shh[576 + lane] = q9.x;
        shh[640 + lane] = qa.x;    shh[704 + lane] = qb.x;
        shh[768 + lane] = qc.x;    shh[832 + lane] = qd.x;
        shh[896 + lane] = qe.x;    shh[960 + lane] = qf.x;
      }
    } else if (tid == 128) {
      // dense partial for step t (wave2 lane0; parallel with publish+poll)
      float s = 0.f;
#pragma unroll
      for (int wv = 0; wv < 16; ++wv) s += psm[wv];
      yp[t * 32 + b] = s;
    }
    __syncthreads();  // bar2: shh now holds h_t
  }
}

__global__ void esn_out(const float* __restrict__ X,
                        const float* __restrict__ wtil,
                        const float* __restrict__ yp,
                        const float* __restrict__ bptr,
                        float* __restrict__ out) {
  const int tid = threadIdx.x;
  const int lane = tid & 63;
  const int wave = tid >> 6;
  const int t = blockIdx.x * 4 + wave;
  float v = wtil[lane] * X[t * 64 + lane];
  if (lane < 32) v += yp[t * 32 + lane];
#pragma unroll
  for (int off = 32; off; off >>= 1) v += __shfl_xor(v, off, 64);
  if (lane == 0) out[t] = v + bptr[0];
}

extern "C" void kernel_launch(void* const* d_in, const int* in_sizes, int n_in,
                              void* d_out, int out_size, void* d_ws, size_t ws_size,
                              hipStream_t stream) {
  const float* X   = (const float*)d_in[0];
  const float* C   = (const float*)d_in[1];
  const float* Win = (const float*)d_in[2];
  const float* W   = (const float*)d_in[3];
  const float* dW  = (const float*)d_in[4];
  const float* db  = (const float*)d_in[5];
  float* ws   = (float*)d_ws;
  float* M    = ws;
  float* wtil = ws + 131072;
  float* yp   = ws + 131200;
  unsigned int* hpub = (unsigned int*)(ws + 393344);

  esn_prep<<<2049, 64, 0, stream>>>(C, Win, dW, M, wtil);

  void* args[] = {(void*)&X, (void*)&M, (void*)&W, (void*)&dW,
                  (void*)&hpub, (void*)&yp};
  (void)hipLaunchCooperativeKernel(reinterpret_cast<void*>(&esn_recur), dim3(32),
                                   dim3(1024), args, 0, stream);

  esn_out<<<1024, 256, 0, stream>>>(X, wtil, yp, db, (float*)d_out);
}

// Round 17
// 8747.179 us; speedup vs baseline: 1.1889x; 1.1889x over previous
//
#include <hip/hip_runtime.h>

#define TT 4096

typedef __attribute__((ext_vector_type(2))) unsigned int u2v;
typedef __attribute__((ext_vector_type(4))) unsigned int u4v;
typedef __attribute__((ext_vector_type(2))) __fp16 f16x2;
typedef __attribute__((ext_vector_type(2))) _Float16 F16x2;
union HU { unsigned int u; f16x2 hf; F16x2 hF; };

// ws layout (float offsets):
//   M    @ 0      : 2048*64 = 131072   (W_in @ C)
//   wtil @ 131072 : 64                 (C^T @ dense_W[:64])
//   yp   @ 131200 : 4096*64 = 262144   (per-WG dense partials, plain stores)
//   hpub @ 393344 : 2 slots * 1024 packets * (u32 data, u32 tag) = 4096 u32
// hpub needs NO init: harness poisons ws to 0xAA -> tag never matches t+1.
//
// FINAL LEDGER (r0-r16):
// CONFIRMED+APPLIED: W in VGPRs (r3, -970us); publisher wave != poller
// wave (r9, -500us); publish = ONE coalesced burst from ONE wave after a
// gather barrier (r1/r2/r6, 3x); half/quarter-wave reduce + broadcast
// h-reads (r14 -360us, r15 -195us).
// FALSIFIED: reader contention (r2/r4 replication, r13 throttling), poll
// sampling quantization (r7), nt/MALL-direct (r8), barrier vmcnt drains
// (r7), participant count (r16: 32 WGs -> FETCH/step UNCHANGED, dur worse
// from doubled compute wall -> detect is a fabric visibility floor).
// CURSED: 256-thread launches (r11/r12), DPP row_bcast (r11).
// Residual ~4000cy/step = cross-XCD system-scope store->load visibility:
// invariant to every protocol lever tested. This kernel is the floor.

__global__ void esn_prep(const float* __restrict__ C,
                         const float* __restrict__ Win,
                         const float* __restrict__ dW,
                         float* __restrict__ M,
                         float* __restrict__ wtil) {
  __shared__ float s[64];
  const int b = blockIdx.x, i = threadIdx.x;
  if (b < 2048) {
    s[i] = Win[b * 64 + i];
    __syncthreads();
    float acc = 0.f;
#pragma unroll 16
    for (int d = 0; d < 64; ++d) acc += s[d] * C[d * 64 + i];
    M[b * 64 + i] = acc;
  } else {
    s[i] = dW[i];
    __syncthreads();
    float acc = 0.f;
    for (int d = 0; d < 64; ++d) acc += s[d] * C[d * 64 + i];
    wtil[i] = acc;
  }
}

// Call-free tanh: tanh(x) = 1 - 2/(exp(2x)+1)
__device__ __forceinline__ float fast_tanh(float x) {
  const float e = __builtin_amdgcn_exp2f(x * 2.8853900817779268f);  // exp(2x)
  return 1.0f - 2.0f * __builtin_amdgcn_rcpf(e + 1.0f);
}

// fp16-pair dot with fp32 accumulate: v_dot2_f32_f16 where available.
__device__ __forceinline__ float fdot2f(const HU a, const HU b, float c) {
#if __has_builtin(__builtin_amdgcn_fdot2)
  return __builtin_amdgcn_fdot2(a.hF, b.hF, c, false);
#else
  return c + (float)a.hf.x * (float)b.hf.x + (float)a.hf.y * (float)b.hf.y;
#endif
}

// 64 WGs x 1024 threads. Waves 8-15 compute (4 rows each, quarter-wave);
// wave0 polls, wave1 publishes, wave2 writes yp; waves 3-7 barrier-idle.
__global__ __launch_bounds__(1024) void esn_recur(
    const float* __restrict__ X, const float* __restrict__ M,
    const float* __restrict__ W, const float* __restrict__ dW,
    unsigned int* __restrict__ hpub, float* __restrict__ yp) {
  __shared__ unsigned int shh[1024];  // 2048 fp16 h as packed pairs
  __shared__ unsigned int pub[16];    // packed h pairs (2 per compute wave)
  __shared__ float psm[8];            // per-compute-wave dense partials
  const int tid = threadIdx.x;
  const int lane = tid & 63;
  const int wave = tid >> 6;
  const int b = blockIdx.x;
  shh[tid] = 0u;  // h_{-1} = 0
  __syncthreads();

  if (wave >= 8) {
    // ================= COMPUTE ROLE =================
    const int cw = wave - 8;       // 0..7
    const int q = lane >> 4;       // quarter 0..3 -> row offset
    const int ql = lane & 15;
    const int row = b * 32 + cw * 4 + q;
    float m[4], dwv[4];
#pragma unroll
    for (int j = 0; j < 4; ++j) m[j] = M[row * 64 + ql + 16 * j];
#pragma unroll
    for (int r = 0; r < 4; ++r) dwv[r] = dW[64 + b * 32 + cw * 4 + r];
    // this lane's W fragment: row's pair-chunks {4ql+64m}, m=0..15
    // -> fp32 elements [8ql+128m .. +7]: two float4 per m. 64 VGPRs.
    u4v w[16];
#pragma unroll
    for (int mm = 0; mm < 16; ++mm) {
      const float* p = W + (size_t)row * 2048 + 128 * mm + 8 * ql;
      const float4 a = *(const float4*)p;
      const float4 c = *(const float4*)(p + 4);
      HU t0, t1, t2, t3;
      t0.hf = __builtin_amdgcn_cvt_pkrtz(a.x, a.y);
      t1.hf = __builtin_amdgcn_cvt_pkrtz(a.z, a.w);
      t2.hf = __builtin_amdgcn_cvt_pkrtz(c.x, c.y);
      t3.hf = __builtin_amdgcn_cvt_pkrtz(c.z, c.w);
      w[mm][0] = t0.u; w[mm][1] = t1.u; w[mm][2] = t2.u; w[mm][3] = t3.u;
    }
    for (int t = 0; t < TT; ++t) {
      // X loads issued at loop top, consumed AFTER the dot phase (~hidden)
      float xr[4];
#pragma unroll
      for (int j = 0; j < 4; ++j) xr[j] = X[t * 64 + ql + 16 * j];
      float acc = 0.f;
#pragma unroll
      for (int mm = 0; mm < 16; ++mm) {
        // lanes ql, ql+16, ql+32, ql+48 read same addr -> 4-way broadcast;
        // across ql: 16B stride -> conflict-free ds_read_b128.
        const u4v hv = *(const u4v*)(shh + 4 * ql + 64 * mm);
#pragma unroll
        for (int k = 0; k < 4; ++k) {
          HU ha, wv;
          ha.u = hv[k]; wv.u = w[mm][k];
          acc = fdot2f(wv, ha, acc);
        }
      }
      acc += m[0] * xr[0] + m[1] * xr[1] + m[2] * xr[2] + m[3] * xr[3];
      // in-quarter reduce (offsets stay within the 16-lane quarter)
#pragma unroll
      for (int off = 8; off; off >>= 1) acc += __shfl_xor(acc, off, 64);
      // gather the 4 quarter-sums to lane 0
      const float s1 = __shfl(acc, 16, 64);
      const float s2 = __shfl(acc, 32, 64);
      const float s3 = __shfl(acc, 48, 64);
      if (lane == 0) {
        const float h0 = fast_tanh(acc);
        const float h1 = fast_tanh(s1);
        const float h2 = fast_tanh(s2);
        const float h3 = fast_tanh(s3);
        HU pa, pb;
        pa.hf = __builtin_amdgcn_cvt_pkrtz(h0, h1);
        pb.hf = __builtin_amdgcn_cvt_pkrtz(h2, h3);
        pub[2 * cw] = pa.u;
        pub[2 * cw + 1] = pb.u;
        psm[cw] = dwv[0] * h0 + dwv[1] * h1 + dwv[2] * h2 + dwv[3] * h3;
      }
      __syncthreads();  // bar1: pub + psm ready; shh reads of step t done
      __syncthreads();  // bar2: shh holds h_t (written by wave0)
    }
  } else {
    // ================= PROTOCOL ROLE =================
    for (int t = 0; t < TT; ++t) {
      __syncthreads();  // bar1
      const unsigned tg = (unsigned)t + 1u;
      unsigned int* slot = hpub + ((t & 1) << 11);
      if (wave == 1) {
        // publish: ONE coalesced 16-packet burst (NOT the poller -- r9 law)
        if (t + 1 < TT && lane < 16) {
          u2v pv; pv.x = pub[lane]; pv.y = tg;
          asm volatile("global_store_dwordx2 %0, %1, off sc0 sc1"
                       :: "v"(slot + 2 * (16 * b + lane)), "v"(pv) : "memory");
        }
      } else if (wave == 0) {
        if (t + 1 < TT) {
          // poll: lane L owns packets {64p+L}; 16 loads in flight/round;
          // vmcnt(0) drains loads only -- never a store ack (r9 law).
          const unsigned int* b0 = slot + 2 * lane;
          const unsigned int* b1 = b0 + 1024;
          u2v q0, q1, q2, q3, q4, q5, q6, q7, q8, q9, qa, qb, qc, qd, qe, qf;
          for (;;) {
            asm volatile(
                "global_load_dwordx2 %0, %16, off sc0 sc1\n\t"
                "global_load_dwordx2 %1, %16, off offset:512 sc0 sc1\n\t"
                "global_load_dwordx2 %2, %16, off offset:1024 sc0 sc1\n\t"
                "global_load_dwordx2 %3, %16, off offset:1536 sc0 sc1\n\t"
                "global_load_dwordx2 %4, %16, off offset:2048 sc0 sc1\n\t"
                "global_load_dwordx2 %5, %16, off offset:2560 sc0 sc1\n\t"
                "global_load_dwordx2 %6, %16, off offset:3072 sc0 sc1\n\t"
                "global_load_dwordx2 %7, %16, off offset:3584 sc0 sc1\n\t"
                "global_load_dwordx2 %8, %17, off sc0 sc1\n\t"
                "global_load_dwordx2 %9, %17, off offset:512 sc0 sc1\n\t"
                "global_load_dwordx2 %10, %17, off offset:1024 sc0 sc1\n\t"
                "global_load_dwordx2 %11, %17, off offset:1536 sc0 sc1\n\t"
                "global_load_dwordx2 %12, %17, off offset:2048 sc0 sc1\n\t"
                "global_load_dwordx2 %13, %17, off offset:2560 sc0 sc1\n\t"
                "global_load_dwordx2 %14, %17, off offset:3072 sc0 sc1\n\t"
                "global_load_dwordx2 %15, %17, off offset:3584 sc0 sc1\n\t"
                "s_waitcnt vmcnt(0)"
                : "=&v"(q0), "=&v"(q1), "=&v"(q2), "=&v"(q3),
                  "=&v"(q4), "=&v"(q5), "=&v"(q6), "=&v"(q7),
                  "=&v"(q8), "=&v"(q9), "=&v"(qa), "=&v"(qb),
                  "=&v"(qc), "=&v"(qd), "=&v"(qe), "=&v"(qf)
                : "v"(b0), "v"(b1)
                : "memory");
            bool ok = (q0.y == tg) && (q1.y == tg) && (q2.y == tg) &&
                      (q3.y == tg) && (q4.y == tg) && (q5.y == tg) &&
                      (q6.y == tg) && (q7.y == tg) && (q8.y == tg) &&
                      (q9.y == tg) && (qa.y == tg) && (qb.y == tg) &&
                      (qc.y == tg) && (qd.y == tg) && (qe.y == tg) &&
                      (qf.y == tg);
            if (__all(ok)) break;
          }
          // repack: shh[64p + lane] -- stride-1 across lanes, conflict-free
          shh[lane] = q0.x;          shh[64 + lane] = q1.x;
          shh[128 + lane] = q2.x;    shh[192 + lane] = q3.x;
          shh[256 + lane] = q4.x;    shh[320 + lane] = q5.x;
          shh[384 + lane] = q6.x;    shh[448 + lane] = q7.x;
          shh[512 + lane] = q8.x;    shh[576 + lane] = q9.x;
          shh[640 + lane] = qa.x;    shh[704 + lane] = qb.x;
          shh[768 + lane] = qc.x;    shh[832 + lane] = qd.x;
          shh[896 + lane] = qe.x;    shh[960 + lane] = qf.x;
        }
      } else if (tid == 128) {
        // dense partial for step t (wave2 lane0; parallel with pub+poll)
        float s = 0.f;
#pragma unroll
        for (int wv = 0; wv < 8; ++wv) s += psm[wv];
        yp[t * 64 + b] = s;
      }
      __syncthreads();  // bar2
    }
  }
}

__global__ void esn_out(const float* __restrict__ X,
                        const float* __restrict__ wtil,
                        const float* __restrict__ yp,
                        const float* __restrict__ bptr,
                        float* __restrict__ out) {
  const int tid = threadIdx.x;
  const int lane = tid & 63;
  const int wave = tid >> 6;
  const int t = blockIdx.x * 4 + wave;
  float v = wtil[lane] * X[t * 64 + lane] + yp[t * 64 + lane];
#pragma unroll
  for (int off = 32; off; off >>= 1) v += __shfl_xor(v, off, 64);
  if (lane == 0) out[t] = v + bptr[0];
}

extern "C" void kernel_launch(void* const* d_in, const int* in_sizes, int n_in,
                              void* d_out, int out_size, void* d_ws, size_t ws_size,
                              hipStream_t stream) {
  const float* X   = (const float*)d_in[0];
  const float* C   = (const float*)d_in[1];
  const float* Win = (const float*)d_in[2];
  const float* W   = (const float*)d_in[3];
  const float* dW  = (const float*)d_in[4];
  const float* db  = (const float*)d_in[5];
  float* ws   = (float*)d_ws;
  float* M    = ws;
  float* wtil = ws + 131072;
  float* yp   = ws + 131200;
  unsigned int* hpub = (unsigned int*)(ws + 393344);

  esn_prep<<<2049, 64, 0, stream>>>(C, Win, dW, M, wtil);

  void* args[] = {(void*)&X, (void*)&M, (void*)&W, (void*)&dW,
                  (void*)&hpub, (void*)&yp};
  (void)hipLaunchCooperativeKernel(reinterpret_cast<void*>(&esn_recur), dim3(64),
                                   dim3(1024), args, 0, stream);

  esn_out<<<1024, 256, 0, stream>>>(X, wtil, yp, db, (float*)d_out);
}